// Round 4
// baseline (163.531 us; speedup 1.0000x reference)
//
#include <hip/hip_runtime.h>
#include <stdint.h>
#include <stddef.h>

typedef _Float16 f16;
typedef __attribute__((ext_vector_type(8))) _Float16 f16x8;
typedef __attribute__((ext_vector_type(4))) _Float16 f16x4;
typedef __attribute__((ext_vector_type(16))) float f32x16;
typedef __attribute__((ext_vector_type(8))) float f32x8v;
typedef __attribute__((ext_vector_type(4))) float floatx4;

#define MFMA(a, b, c) __builtin_amdgcn_mfma_f32_32x32x16_f16((a), (b), (c), 0, 0, 0)

typedef const __attribute__((address_space(1))) void gvoid_t;
typedef __attribute__((address_space(3))) void svoid_t;

__device__ __forceinline__ void gload_lds16(const void* g, void* l) {
  // wave-uniform LDS base; HW writes lane's 16B at base + lane*16
  __builtin_amdgcn_global_load_lds((gvoid_t*)g, (svoid_t*)l, 16, 0, 0);
}

// ---------------- W (KxN) fp32 -> Wt (NxK) fp16, LDS tiled ----------------
__global__ __launch_bounds__(256) void k_transpose_cvt(const float* __restrict__ W,
                                                       f16* __restrict__ Wt, int K, int N) {
  __shared__ float t[32][33];
  int k0 = blockIdx.x * 32, n0 = blockIdx.y * 32;
  int tx = threadIdx.x & 31, ty = threadIdx.x >> 5;  // 32 x 8
#pragma unroll
  for (int i = 0; i < 4; ++i)
    t[ty + 8 * i][tx] = W[(size_t)(k0 + ty + 8 * i) * N + n0 + tx];
  __syncthreads();
#pragma unroll
  for (int i = 0; i < 4; ++i)
    Wt[(size_t)(n0 + ty + 8 * i) * K + k0 + tx] = (f16)t[tx][ty + 8 * i];
}

// ---------------- projection GEMM, fp32 A staging, fused RoPE epilogue ----------------
// A = x (16384x1024 fp32), Bt = Wth (5 matrices of 128x1024 f16). blockIdx.x = matrix id.
// Waves stacked in M (wave*32 rows, full N=128) so RoPE pair (d, d+64) is
// acc[nb] / acc[nb+2] in the SAME lane.
__global__ __launch_bounds__(256, 2) void k_proj(const float* __restrict__ X,
                                                 const f16* __restrict__ Bt,
                                                 const float* __restrict__ cosp,
                                                 const float* __restrict__ sinp,
                                                 f16* __restrict__ q1h, f16* __restrict__ q2h,
                                                 f16* __restrict__ k1h, f16* __restrict__ k2h,
                                                 f16* __restrict__ vh) {
  __shared__ __align__(16) float Af[128 * 64];  // 32 KB fp32 A tile
  __shared__ __align__(16) f16 Bs[128 * 64];    // 16 KB f16 B tile
  int tid = threadIdx.x;
  int wave = tid >> 6, lane = tid & 63;
  int m0 = blockIdx.y * 128, n0 = blockIdx.x;  // n0: 0..4 matrix id
  int wm = wave * 32;
  int rl = lane & 31, h = lane >> 5;
  int srow = lane >> 3, sslot = lane & 7;      // B staging (8 rows x 8 slots)
  int arow = lane >> 4, aslot = lane & 15;     // A staging (4 rows x 16 slots)
  const f16* Bmat = Bt + (size_t)n0 * 128 * 1024;

  f32x16 acc[4];
#pragma unroll
  for (int nb = 0; nb < 4; ++nb)
#pragma unroll
    for (int r = 0; r < 16; ++r) acc[nb][r] = 0.f;

  for (int k0 = 0; k0 < 1024; k0 += 64) {
    __syncthreads();
    // A: 32 chunks of 4 rows (1 KB each); 32B-granule XOR swizzle on source
#pragma unroll
    for (int c = 0; c < 8; ++c) {
      int chunk = c * 4 + wave;
      int r = chunk * 4 + arow;
      int src16 = (((aslot >> 1) ^ (r & 7)) << 1) | (aslot & 1);
      gload_lds16(X + (size_t)(m0 + r) * 1024 + k0 + src16 * 4, Af + chunk * 256);
    }
    // B: 16 chunks of 8 rows
#pragma unroll
    for (int c = 0; c < 4; ++c) {
      int chunk = c * 4 + wave;
      int r = chunk * 8 + srow;
      int cb = sslot ^ (r & 7);
      gload_lds16(Bmat + (size_t)r * 1024 + k0 + cb * 8, Bs + chunk * 512);
    }
    __syncthreads();

#pragma unroll
    for (int kb = 0; kb < 4; ++kb) {
      int s = 2 * kb + h;
      int ra = wm + rl;
      f32x8v a8 = *(const f32x8v*)(Af + ra * 64 + ((s ^ (ra & 7)) * 8));
      f16x8 af;
#pragma unroll
      for (int e = 0; e < 8; ++e) af[e] = (f16)a8[e];
      f16x8 bf[4];
#pragma unroll
      for (int nb = 0; nb < 4; ++nb) {
        int rb = nb * 32 + rl;
        bf[nb] = *(const f16x8*)(Bs + rb * 64 + (s ^ (rb & 7)) * 8);
      }
#pragma unroll
      for (int nb = 0; nb < 4; ++nb) acc[nb] = MFMA(af, bf[nb], acc[nb]);
    }
  }

  if (n0 == 4) {  // V: plain cvt store
#pragma unroll
    for (int r = 0; r < 16; ++r) {
      int irow = (r & 3) + 8 * (r >> 2) + 4 * h;
      int gr = m0 + wm + irow;
#pragma unroll
      for (int nb = 0; nb < 4; ++nb)
        vh[(size_t)gr * 128 + nb * 32 + rl] = (f16)acc[nb][r];
    }
  } else {
    f16* outp = (n0 == 0) ? q1h : (n0 == 1) ? q2h : (n0 == 2) ? k1h : k2h;
#pragma unroll
    for (int r = 0; r < 16; ++r) {
      int irow = (r & 3) + 8 * (r >> 2) + 4 * h;
      int gr = m0 + wm + irow;
      int s = gr & 4095;
#pragma unroll
      for (int nb = 0; nb < 2; ++nb) {
        int d = nb * 32 + rl;
        float c = cosp[s * 64 + d], sn = sinp[s * 64 + d];
        float a = acc[nb][r], bb = acc[nb + 2][r];
        outp[(size_t)gr * 128 + d]      = (f16)(a * c - bb * sn);
        outp[(size_t)gr * 128 + 64 + d] = (f16)(a * sn + bb * c);
      }
    }
  }
}

// ---------------- V transpose (f16): vh(16384x128) -> vt[b][d][s] ----------------
__global__ __launch_bounds__(256) void k_vtrans16(const f16* __restrict__ vh,
                                                  f16* __restrict__ vt) {
  __shared__ unsigned short t[32][33];
  int r0 = blockIdx.x * 32, d0 = blockIdx.y * 32;
  int tx = threadIdx.x & 31, ty = threadIdx.x >> 5;
#pragma unroll
  for (int i = 0; i < 4; ++i)
    t[ty + 8 * i][tx] = ((const unsigned short*)vh)[(size_t)(r0 + ty + 8 * i) * 128 + d0 + tx];
  __syncthreads();
  int b = r0 >> 12, s0 = r0 & 4095;
#pragma unroll
  for (int i = 0; i < 4; ++i)
    ((unsigned short*)vt)[((size_t)(b * 128 + d0 + ty + 8 * i)) * 4096 + s0 + tx] =
        t[tx][ty + 8 * i];
}

// ---------------- S-phase: P = mask(S1*S2)/128, packed lower-triangle tiles ----------------
// grid: 4 batches * 528 tile-pairs, all equal work. Tile (i,j): Q rows i*128.., K rows j*128..
__global__ __launch_bounds__(256, 2) void k_s(const f16* __restrict__ q1h,
                                              const f16* __restrict__ q2h,
                                              const f16* __restrict__ k1h,
                                              const f16* __restrict__ k2h,
                                              f16* __restrict__ P) {
  __shared__ __align__(16) f16 A1[128 * 64];
  __shared__ __align__(16) f16 A2[128 * 64];
  __shared__ __align__(16) f16 B1[128 * 64];
  __shared__ __align__(16) f16 B2[128 * 64];
  int bid0 = blockIdx.x;
  int bid = (bid0 & 7) * 264 + (bid0 >> 3);  // XCD-contiguous chunks (2112 = 8*264)
  int b = bid / 528, t = bid % 528;
  int i = (int)((sqrtf(8.f * t + 1.f) - 1.f) * 0.5f);
  if ((i + 1) * (i + 2) / 2 <= t) ++i;
  if (i * (i + 1) / 2 > t) --i;
  int j = t - i * (i + 1) / 2;

  int tid = threadIdx.x;
  int wave = tid >> 6, lane = tid & 63;
  int wm = (wave >> 1) * 64, wn = (wave & 1) * 64;
  int rl = lane & 31, h = lane >> 5;
  int srow = lane >> 3, sslot = lane & 7;
  size_t rowA = (size_t)b * 4096 + i * 128;
  size_t rowB = (size_t)b * 4096 + j * 128;

  f32x16 acc1[2][2], acc2[2][2];
#pragma unroll
  for (int mb = 0; mb < 2; ++mb)
#pragma unroll
    for (int nb = 0; nb < 2; ++nb)
#pragma unroll
      for (int r = 0; r < 16; ++r) { acc1[mb][nb][r] = 0.f; acc2[mb][nb][r] = 0.f; }

  for (int k0 = 0; k0 < 128; k0 += 64) {
    __syncthreads();
#pragma unroll
    for (int c = 0; c < 4; ++c) {
      int chunk = c * 4 + wave;
      int r = chunk * 8 + srow;
      int cb = sslot ^ (r & 7);
      gload_lds16(q1h + (rowA + r) * 128 + k0 + cb * 8, A1 + chunk * 512);
      gload_lds16(q2h + (rowA + r) * 128 + k0 + cb * 8, A2 + chunk * 512);
      gload_lds16(k1h + (rowB + r) * 128 + k0 + cb * 8, B1 + chunk * 512);
      gload_lds16(k2h + (rowB + r) * 128 + k0 + cb * 8, B2 + chunk * 512);
    }
    __syncthreads();

#pragma unroll
    for (int kb = 0; kb < 4; ++kb) {
      int s = 2 * kb + h;
      f16x8 a1f[2], a2f[2], b1f[2], b2f[2];
#pragma unroll
      for (int mb = 0; mb < 2; ++mb) {
        int r = wm + mb * 32 + rl;
        int off = r * 64 + (s ^ (r & 7)) * 8;
        a1f[mb] = *(const f16x8*)(A1 + off);
        a2f[mb] = *(const f16x8*)(A2 + off);
      }
#pragma unroll
      for (int nb = 0; nb < 2; ++nb) {
        int r = wn + nb * 32 + rl;
        int off = r * 64 + (s ^ (r & 7)) * 8;
        b1f[nb] = *(const f16x8*)(B1 + off);
        b2f[nb] = *(const f16x8*)(B2 + off);
      }
#pragma unroll
      for (int mb = 0; mb < 2; ++mb)
#pragma unroll
        for (int nb = 0; nb < 2; ++nb) {
          acc1[mb][nb] = MFMA(a1f[mb], b1f[nb], acc1[mb][nb]);
          acc2[mb][nb] = MFMA(a2f[mb], b2f[nb], acc2[mb][nb]);
        }
    }
  }

  f16* pt = P + ((size_t)b * 528 + t) * 16384;
  bool diag = (i == j);
#pragma unroll
  for (int mb = 0; mb < 2; ++mb)
#pragma unroll
    for (int nb = 0; nb < 2; ++nb)
#pragma unroll
      for (int r = 0; r < 16; ++r) {
        int row_l = wm + mb * 32 + (r & 3) + 8 * (r >> 2) + 4 * h;
        int col_l = wn + nb * 32 + rl;
        float p = acc1[mb][nb][r] * acc2[mb][nb][r] * (1.0f / 128.0f);
        if (diag && col_l > row_l) p = 0.f;
        pt[(size_t)row_l * 128 + col_l] = (f16)p;
      }
}

// ---------------- PV-phase: O_partial = P_packed * V^T, split-K over 1024-key chunks ----------------
__global__ __launch_bounds__(256, 2) void k_pv(const f16* __restrict__ P,
                                               const f16* __restrict__ vt,
                                               f16* __restrict__ o0, f16* __restrict__ o1,
                                               f16* __restrict__ o2, f16* __restrict__ o3) {
  __shared__ __align__(16) f16 As[128 * 64];
  __shared__ __align__(16) f16 Bs[128 * 64];
  int bid = blockIdx.x;
  int b = bid / 80, c = bid % 80;
  int qt, s;
  if (c < 8)       { qt = c;                 s = 0; }
  else if (c < 24) { int t = c - 8;  qt = 8  + (t >> 1); s = t & 1; }
  else if (c < 48) { int t = c - 24; qt = 16 + t / 3;    s = t - 3 * (t / 3); }
  else             { int t = c - 48; qt = 24 + (t >> 2); s = t & 3; }
  int tq = qt * (qt + 1) / 2;
  const f16* Pb = P + (size_t)b * 528 * 16384;
  const f16* vb = vt + (size_t)b * 128 * 4096;
  int kbase = s * 1024;
  int kend = (qt + 1) * 128 < kbase + 1024 ? (qt + 1) * 128 : kbase + 1024;

  int tid = threadIdx.x;
  int wave = tid >> 6, lane = tid & 63;
  int wm = (wave >> 1) * 64, wn = (wave & 1) * 64;
  int rl = lane & 31, h = lane >> 5;
  int srow = lane >> 3, sslot = lane & 7;

  f32x16 acc[2][2];
#pragma unroll
  for (int mb = 0; mb < 2; ++mb)
#pragma unroll
    for (int nb = 0; nb < 2; ++nb)
#pragma unroll
      for (int r = 0; r < 16; ++r) acc[mb][nb][r] = 0.f;

  for (int k0 = kbase; k0 < kend; k0 += 64) {
    int jt = k0 >> 7, koff = k0 & 127;
    const f16* Pt = Pb + (size_t)(tq + jt) * 16384;
    __syncthreads();
#pragma unroll
    for (int c4 = 0; c4 < 4; ++c4) {
      int chunk = c4 * 4 + wave;
      int r = chunk * 8 + srow;
      int cb = sslot ^ (r & 7);
      gload_lds16(Pt + (size_t)r * 128 + koff + cb * 8, As + chunk * 512);
      gload_lds16(vb + (size_t)r * 4096 + k0 + cb * 8, Bs + chunk * 512);
    }
    __syncthreads();

#pragma unroll
    for (int kb = 0; kb < 4; ++kb) {
      int sidx = 2 * kb + h;
      f16x8 af[2], bf[2];
#pragma unroll
      for (int mb = 0; mb < 2; ++mb) {
        int r = wm + mb * 32 + rl;
        af[mb] = *(const f16x8*)(As + r * 64 + (sidx ^ (r & 7)) * 8);
      }
#pragma unroll
      for (int nb = 0; nb < 2; ++nb) {
        int r = wn + nb * 32 + rl;
        bf[nb] = *(const f16x8*)(Bs + r * 64 + (sidx ^ (r & 7)) * 8);
      }
#pragma unroll
      for (int mb = 0; mb < 2; ++mb)
#pragma unroll
        for (int nb = 0; nb < 2; ++nb)
          acc[mb][nb] = MFMA(af[mb], bf[nb], acc[mb][nb]);
    }
  }

  f16* op = (s == 0) ? o0 : (s == 1) ? o1 : (s == 2) ? o2 : o3;
#pragma unroll
  for (int mb = 0; mb < 2; ++mb)
#pragma unroll
    for (int nb = 0; nb < 2; ++nb)
#pragma unroll
      for (int r = 0; r < 16; ++r) {
        int gr = b * 4096 + qt * 128 + wm + mb * 32 + (r & 3) + 8 * (r >> 2) + 4 * h;
        op[(size_t)gr * 128 + wn + nb * 32 + rl] = (f16)acc[mb][nb][r];
      }
}

// ---------------- output projection with fused partial-combine A staging ----------------
// C(16384x1024 fp32) = (sum_s o_s)(16384x128) * Woth(1024x128)^T
__global__ __launch_bounds__(256, 2) void k_gout(const f16* __restrict__ o0,
                                                 const f16* __restrict__ o1,
                                                 const f16* __restrict__ o2,
                                                 const f16* __restrict__ o3,
                                                 const f16* __restrict__ Bt,
                                                 float* __restrict__ C) {
  __shared__ __align__(16) f16 As[128 * 64];
  __shared__ __align__(16) f16 Bs[128 * 64];
  int tid = threadIdx.x;
  int wave = tid >> 6, lane = tid & 63;
  int m0 = blockIdx.y * 128, n0 = blockIdx.x * 128;
  int wm = (wave >> 1) * 64, wn = (wave & 1) * 64;
  int rl = lane & 31, h = lane >> 5;
  int srow = lane >> 3, sslot = lane & 7;
  int qt = (m0 >> 7) & 31;
  int ns = (qt >> 3) + 1;  // number of PV split partials covering this row block
  const f16* srcs[4] = {o0, o1, o2, o3};

  f32x16 acc[2][2];
#pragma unroll
  for (int mb = 0; mb < 2; ++mb)
#pragma unroll
    for (int nb = 0; nb < 2; ++nb)
#pragma unroll
      for (int r = 0; r < 16; ++r) acc[mb][nb][r] = 0.f;

  for (int k0 = 0; k0 < 128; k0 += 64) {
    __syncthreads();
#pragma unroll
    for (int c = 0; c < 4; ++c) {
      int chunk = c * 4 + wave;
      int r = chunk * 8 + srow;
      // A: reg-stage sum of partials, swizzled ds_write
      float sum[8];
#pragma unroll
      for (int e = 0; e < 8; ++e) sum[e] = 0.f;
#pragma unroll
      for (int p = 0; p < 4; ++p) {
        if (p < ns) {
          f16x8 v = *(const f16x8*)(srcs[p] + (size_t)(m0 + r) * 128 + k0 + sslot * 8);
#pragma unroll
          for (int e = 0; e < 8; ++e) sum[e] += (float)v[e];
        }
      }
      f16x8 w;
#pragma unroll
      for (int e = 0; e < 8; ++e) w[e] = (f16)sum[e];
      *(f16x8*)(As + r * 64 + (sslot ^ (r & 7)) * 8) = w;
      // B: async stage
      int cb = sslot ^ (r & 7);
      gload_lds16(Bt + (size_t)(n0 + r) * 128 + k0 + cb * 8, Bs + chunk * 512);
    }
    __syncthreads();

#pragma unroll
    for (int kb = 0; kb < 4; ++kb) {
      int s = 2 * kb + h;
      f16x8 af[2], bf[2];
#pragma unroll
      for (int mb = 0; mb < 2; ++mb) {
        int r = wm + mb * 32 + rl;
        af[mb] = *(const f16x8*)(As + r * 64 + (s ^ (r & 7)) * 8);
      }
#pragma unroll
      for (int nb = 0; nb < 2; ++nb) {
        int r = wn + nb * 32 + rl;
        bf[nb] = *(const f16x8*)(Bs + r * 64 + (s ^ (r & 7)) * 8);
      }
#pragma unroll
      for (int mb = 0; mb < 2; ++mb)
#pragma unroll
        for (int nb = 0; nb < 2; ++nb)
          acc[mb][nb] = MFMA(af[mb], bf[nb], acc[mb][nb]);
    }
  }

#pragma unroll
  for (int mb = 0; mb < 2; ++mb)
#pragma unroll
    for (int nb = 0; nb < 2; ++nb)
#pragma unroll
      for (int r = 0; r < 16; ++r) {
        int i = m0 + wm + mb * 32 + (r & 3) + 8 * (r >> 2) + 4 * h;
        int j = n0 + wn + nb * 32 + rl;
        C[(size_t)i * 1024 + j] = acc[mb][nb][r];
      }
}

// ---------------- launch ----------------
extern "C" void kernel_launch(void* const* d_in, const int* in_sizes, int n_in,
                              void* d_out, int out_size, void* d_ws, size_t ws_size,
                              hipStream_t stream) {
  (void)in_sizes; (void)n_in; (void)out_size; (void)ws_size;
  const float* x  = (const float*)d_in[0];
  const float* cp = (const float*)d_in[1];
  const float* sp = (const float*)d_in[2];
  // d_in[3] = causal_mask (unused; mask computed analytically)
  const float* W[5] = {(const float*)d_in[4], (const float*)d_in[5], (const float*)d_in[6],
                       (const float*)d_in[7], (const float*)d_in[8]};
  const float* Wo = (const float*)d_in[9];
  float* out = (float*)d_out;
  char* ws = (char*)d_ws;

  // workspace layout (bytes):
  // [0, 16M): o0..o3 f16 PV partials (4 MB each)
  // [32M, 58M): q1h,q2h,k1h,k2h,vh,vt (4 MB each)
  // then Wth (1.25M), Woth (0.25M), P packed (69M)
  const size_t OFF_H    = 33554432;
  const size_t OFF_WTH  = OFF_H + 6 * 4194304;
  const size_t OFF_WOTH = OFF_WTH + 1310720;
  const size_t OFF_P    = OFF_WOTH + 262144;
  f16*   o0   = (f16*)(ws + 0);
  f16*   o1   = (f16*)(ws + 4194304);
  f16*   o2   = (f16*)(ws + 8388608);
  f16*   o3   = (f16*)(ws + 12582912);
  f16*   q1h  = (f16*)(ws + OFF_H + 0 * 4194304);
  f16*   q2h  = (f16*)(ws + OFF_H + 1 * 4194304);
  f16*   k1h  = (f16*)(ws + OFF_H + 2 * 4194304);
  f16*   k2h  = (f16*)(ws + OFF_H + 3 * 4194304);
  f16*   vh   = (f16*)(ws + OFF_H + 4 * 4194304);
  f16*   vt   = (f16*)(ws + OFF_H + 5 * 4194304);
  f16*   Wth  = (f16*)(ws + OFF_WTH);
  f16*   Woth = (f16*)(ws + OFF_WOTH);
  f16*   P    = (f16*)(ws + OFF_P);

  // 1) weight transposes (fp32 KxN -> fp16 NxK)
  for (int w = 0; w < 5; ++w)
    k_transpose_cvt<<<dim3(32, 4), 256, 0, stream>>>(W[w], Wth + (size_t)w * 128 * 1024, 1024, 128);
  k_transpose_cvt<<<dim3(4, 32), 256, 0, stream>>>(Wo, Woth, 128, 1024);
  // 2) projections from fp32 x with fused RoPE epilogue
  k_proj<<<dim3(5, 128), 256, 0, stream>>>(x, Wth, cp, sp, q1h, q2h, k1h, k2h, vh);
  // 3) V transpose
  k_vtrans16<<<dim3(512, 4), 256, 0, stream>>>(vh, vt);
  // 4) S-phase (packed triangular P)
  k_s<<<2112, 256, 0, stream>>>(q1h, q2h, k1h, k2h, P);
  // 5) PV-phase (split-K f16 partials)
  k_pv<<<320, 256, 0, stream>>>(P, vt, o0, o1, o2, o3);
  // 6) output projection with fused partial combine
  k_gout<<<dim3(8, 128), 256, 0, stream>>>(o0, o1, o2, o3, Woth, out);
}

// Round 5
// 151.371 us; speedup vs baseline: 1.0803x; 1.0803x over previous
//
#include <hip/hip_runtime.h>
#include <stdint.h>
#include <stddef.h>

typedef _Float16 f16;
typedef __attribute__((ext_vector_type(8))) _Float16 f16x8;
typedef __attribute__((ext_vector_type(4))) _Float16 f16x4;
typedef __attribute__((ext_vector_type(16))) float f32x16;
typedef __attribute__((ext_vector_type(4))) float floatx4;

#define MFMA(a, b, c) __builtin_amdgcn_mfma_f32_32x32x16_f16((a), (b), (c), 0, 0, 0)

typedef const __attribute__((address_space(1))) void gvoid_t;
typedef __attribute__((address_space(3))) void svoid_t;

__device__ __forceinline__ void gload_lds16(const void* g, void* l) {
  // wave-uniform LDS base; HW writes lane's 16B at base + lane*16
  __builtin_amdgcn_global_load_lds((gvoid_t*)g, (svoid_t*)l, 16, 0, 0);
}

// ---------------- fp32 -> fp16 convert ----------------
__global__ __launch_bounds__(256) void k_cvt_f16(const float* __restrict__ in,
                                                 f16* __restrict__ out, int n4) {
  int i = blockIdx.x * 256 + threadIdx.x;
  if (i < n4) {
    floatx4 v = ((const floatx4*)in)[i];
    f16x4 o;
    o[0] = (f16)v[0]; o[1] = (f16)v[1]; o[2] = (f16)v[2]; o[3] = (f16)v[3];
    ((f16x4*)out)[i] = o;
  }
}

// ---------------- W (KxN) fp32 -> Wt (NxK) fp16, LDS tiled ----------------
__global__ __launch_bounds__(256) void k_transpose_cvt(const float* __restrict__ W,
                                                       f16* __restrict__ Wt, int K, int N) {
  __shared__ float t[32][33];
  int k0 = blockIdx.x * 32, n0 = blockIdx.y * 32;
  int tx = threadIdx.x & 31, ty = threadIdx.x >> 5;  // 32 x 8
#pragma unroll
  for (int i = 0; i < 4; ++i)
    t[ty + 8 * i][tx] = W[(size_t)(k0 + ty + 8 * i) * N + n0 + tx];
  __syncthreads();
#pragma unroll
  for (int i = 0; i < 4; ++i)
    Wt[(size_t)(n0 + ty + 8 * i) * K + k0 + tx] = (f16)t[tx][ty + 8 * i];
}

// ---------------- projection GEMM (f16 A), XCD-group swizzle, fused RoPE ----------------
// A = xh (16384x1024 f16), Bt = Wth (5 matrices of 128x1024 f16).
// 1-D grid of 640; bid mapping puts the 5 matrix-blocks of one 128-row x-panel
// on the SAME XCD in adjacent issue slots -> panel served from that XCD's L2.
__global__ __launch_bounds__(256, 2) void k_proj(const f16* __restrict__ A,
                                                 const f16* __restrict__ Bt,
                                                 const float* __restrict__ cosp,
                                                 const float* __restrict__ sinp,
                                                 f16* __restrict__ q1h, f16* __restrict__ q2h,
                                                 f16* __restrict__ k1h, f16* __restrict__ k2h,
                                                 f16* __restrict__ vh) {
  __shared__ __align__(16) f16 As[128 * 64];
  __shared__ __align__(16) f16 Bs[128 * 64];
  int bid = blockIdx.x;
  int c8 = bid & 7, t = bid >> 3;          // t in 0..79
  int n0 = t % 5;                          // matrix id
  int m0 = (c8 + 8 * (t / 5)) * 128;       // row panel: 5 consecutive turns of XCD c8
  int tid = threadIdx.x;
  int wave = tid >> 6, lane = tid & 63;
  int wm = wave * 32;
  int rl = lane & 31, h = lane >> 5;
  int srow = lane >> 3, sslot = lane & 7;
  const f16* Bmat = Bt + (size_t)n0 * 128 * 1024;

  f32x16 acc[4];
#pragma unroll
  for (int nb = 0; nb < 4; ++nb)
#pragma unroll
    for (int r = 0; r < 16; ++r) acc[nb][r] = 0.f;

  for (int k0 = 0; k0 < 1024; k0 += 64) {
    __syncthreads();
#pragma unroll
    for (int c = 0; c < 4; ++c) {
      int chunk = c * 4 + wave;
      int r = chunk * 8 + srow;
      int cb = sslot ^ (r & 7);
      gload_lds16(A + (size_t)(m0 + r) * 1024 + k0 + cb * 8, As + chunk * 512);
      gload_lds16(Bmat + (size_t)r * 1024 + k0 + cb * 8, Bs + chunk * 512);
    }
    __syncthreads();

#pragma unroll
    for (int kb = 0; kb < 4; ++kb) {
      int s = 2 * kb + h;
      int ra = wm + rl;
      f16x8 af = *(const f16x8*)(As + ra * 64 + (s ^ (ra & 7)) * 8);
      f16x8 bf[4];
#pragma unroll
      for (int nb = 0; nb < 4; ++nb) {
        int rb = nb * 32 + rl;
        bf[nb] = *(const f16x8*)(Bs + rb * 64 + (s ^ (rb & 7)) * 8);
      }
#pragma unroll
      for (int nb = 0; nb < 4; ++nb) acc[nb] = MFMA(af, bf[nb], acc[nb]);
    }
  }

  if (n0 == 4) {  // V: plain cvt store
#pragma unroll
    for (int r = 0; r < 16; ++r) {
      int irow = (r & 3) + 8 * (r >> 2) + 4 * h;
      int gr = m0 + wm + irow;
#pragma unroll
      for (int nb = 0; nb < 4; ++nb)
        vh[(size_t)gr * 128 + nb * 32 + rl] = (f16)acc[nb][r];
    }
  } else {
    f16* outp = (n0 == 0) ? q1h : (n0 == 1) ? q2h : (n0 == 2) ? k1h : k2h;
#pragma unroll
    for (int r = 0; r < 16; ++r) {
      int irow = (r & 3) + 8 * (r >> 2) + 4 * h;
      int gr = m0 + wm + irow;
      int s = gr & 4095;
#pragma unroll
      for (int nb = 0; nb < 2; ++nb) {
        int d = nb * 32 + rl;
        float c = cosp[s * 64 + d], sn = sinp[s * 64 + d];
        float a = acc[nb][r], bb = acc[nb + 2][r];
        outp[(size_t)gr * 128 + d]      = (f16)(a * c - bb * sn);
        outp[(size_t)gr * 128 + 64 + d] = (f16)(a * sn + bb * c);
      }
    }
  }
}

// ---------------- V transpose (f16): vh(16384x128) -> vt[b][d][s] ----------------
__global__ __launch_bounds__(256) void k_vtrans16(const f16* __restrict__ vh,
                                                  f16* __restrict__ vt) {
  __shared__ unsigned short t[32][33];
  int r0 = blockIdx.x * 32, d0 = blockIdx.y * 32;
  int tx = threadIdx.x & 31, ty = threadIdx.x >> 5;
#pragma unroll
  for (int i = 0; i < 4; ++i)
    t[ty + 8 * i][tx] = ((const unsigned short*)vh)[(size_t)(r0 + ty + 8 * i) * 128 + d0 + tx];
  __syncthreads();
  int b = r0 >> 12, s0 = r0 & 4095;
#pragma unroll
  for (int i = 0; i < 4; ++i)
    ((unsigned short*)vt)[((size_t)(b * 128 + d0 + ty + 8 * i)) * 4096 + s0 + tx] =
        t[tx][ty + 8 * i];
}

// ---------------- S-phase: P = mask(S1*S2)/128, packed lower-triangle tiles ----------------
__global__ __launch_bounds__(256, 2) void k_s(const f16* __restrict__ q1h,
                                              const f16* __restrict__ q2h,
                                              const f16* __restrict__ k1h,
                                              const f16* __restrict__ k2h,
                                              f16* __restrict__ P) {
  __shared__ __align__(16) f16 A1[128 * 64];
  __shared__ __align__(16) f16 A2[128 * 64];
  __shared__ __align__(16) f16 B1[128 * 64];
  __shared__ __align__(16) f16 B2[128 * 64];
  int bid0 = blockIdx.x;
  int bid = (bid0 & 7) * 264 + (bid0 >> 3);  // XCD-contiguous chunks (2112 = 8*264)
  int b = bid / 528, t = bid % 528;
  int i = (int)((sqrtf(8.f * t + 1.f) - 1.f) * 0.5f);
  if ((i + 1) * (i + 2) / 2 <= t) ++i;
  if (i * (i + 1) / 2 > t) --i;
  int j = t - i * (i + 1) / 2;

  int tid = threadIdx.x;
  int wave = tid >> 6, lane = tid & 63;
  int wm = (wave >> 1) * 64, wn = (wave & 1) * 64;
  int rl = lane & 31, h = lane >> 5;
  int srow = lane >> 3, sslot = lane & 7;
  size_t rowA = (size_t)b * 4096 + i * 128;
  size_t rowB = (size_t)b * 4096 + j * 128;

  f32x16 acc1[2][2], acc2[2][2];
#pragma unroll
  for (int mb = 0; mb < 2; ++mb)
#pragma unroll
    for (int nb = 0; nb < 2; ++nb)
#pragma unroll
      for (int r = 0; r < 16; ++r) { acc1[mb][nb][r] = 0.f; acc2[mb][nb][r] = 0.f; }

  for (int k0 = 0; k0 < 128; k0 += 64) {
    __syncthreads();
#pragma unroll
    for (int c = 0; c < 4; ++c) {
      int chunk = c * 4 + wave;
      int r = chunk * 8 + srow;
      int cb = sslot ^ (r & 7);
      gload_lds16(q1h + (rowA + r) * 128 + k0 + cb * 8, A1 + chunk * 512);
      gload_lds16(q2h + (rowA + r) * 128 + k0 + cb * 8, A2 + chunk * 512);
      gload_lds16(k1h + (rowB + r) * 128 + k0 + cb * 8, B1 + chunk * 512);
      gload_lds16(k2h + (rowB + r) * 128 + k0 + cb * 8, B2 + chunk * 512);
    }
    __syncthreads();

#pragma unroll
    for (int kb = 0; kb < 4; ++kb) {
      int s = 2 * kb + h;
      f16x8 a1f[2], a2f[2], b1f[2], b2f[2];
#pragma unroll
      for (int mb = 0; mb < 2; ++mb) {
        int r = wm + mb * 32 + rl;
        int off = r * 64 + (s ^ (r & 7)) * 8;
        a1f[mb] = *(const f16x8*)(A1 + off);
        a2f[mb] = *(const f16x8*)(A2 + off);
      }
#pragma unroll
      for (int nb = 0; nb < 2; ++nb) {
        int r = wn + nb * 32 + rl;
        int off = r * 64 + (s ^ (r & 7)) * 8;
        b1f[nb] = *(const f16x8*)(B1 + off);
        b2f[nb] = *(const f16x8*)(B2 + off);
      }
#pragma unroll
      for (int mb = 0; mb < 2; ++mb)
#pragma unroll
        for (int nb = 0; nb < 2; ++nb) {
          acc1[mb][nb] = MFMA(a1f[mb], b1f[nb], acc1[mb][nb]);
          acc2[mb][nb] = MFMA(a2f[mb], b2f[nb], acc2[mb][nb]);
        }
    }
  }

  f16* pt = P + ((size_t)b * 528 + t) * 16384;
  bool diag = (i == j);
#pragma unroll
  for (int mb = 0; mb < 2; ++mb)
#pragma unroll
    for (int nb = 0; nb < 2; ++nb)
#pragma unroll
      for (int r = 0; r < 16; ++r) {
        int row_l = wm + mb * 32 + (r & 3) + 8 * (r >> 2) + 4 * h;
        int col_l = wn + nb * 32 + rl;
        float p = acc1[mb][nb][r] * acc2[mb][nb][r] * (1.0f / 128.0f);
        if (diag && col_l > row_l) p = 0.f;
        pt[(size_t)row_l * 128 + col_l] = (f16)p;
      }
}

// ---------------- PV-phase: O_partial = P_packed * V^T, split-K over 1024-key chunks ----------------
__global__ __launch_bounds__(256, 2) void k_pv(const f16* __restrict__ P,
                                               const f16* __restrict__ vt,
                                               f16* __restrict__ o0, f16* __restrict__ o1,
                                               f16* __restrict__ o2, f16* __restrict__ o3) {
  __shared__ __align__(16) f16 As[128 * 64];
  __shared__ __align__(16) f16 Bs[128 * 64];
  int bid = blockIdx.x;
  int b = bid / 80, c = bid % 80;
  int qt, s;
  if (c < 8)       { qt = c;                 s = 0; }
  else if (c < 24) { int t = c - 8;  qt = 8  + (t >> 1); s = t & 1; }
  else if (c < 48) { int t = c - 24; qt = 16 + t / 3;    s = t - 3 * (t / 3); }
  else             { int t = c - 48; qt = 24 + (t >> 2); s = t & 3; }
  int tq = qt * (qt + 1) / 2;
  const f16* Pb = P + (size_t)b * 528 * 16384;
  const f16* vb = vt + (size_t)b * 128 * 4096;
  int kbase = s * 1024;
  int kend = (qt + 1) * 128 < kbase + 1024 ? (qt + 1) * 128 : kbase + 1024;

  int tid = threadIdx.x;
  int wave = tid >> 6, lane = tid & 63;
  int wm = (wave >> 1) * 64, wn = (wave & 1) * 64;
  int rl = lane & 31, h = lane >> 5;
  int srow = lane >> 3, sslot = lane & 7;

  f32x16 acc[2][2];
#pragma unroll
  for (int mb = 0; mb < 2; ++mb)
#pragma unroll
    for (int nb = 0; nb < 2; ++nb)
#pragma unroll
      for (int r = 0; r < 16; ++r) acc[mb][nb][r] = 0.f;

  for (int k0 = kbase; k0 < kend; k0 += 64) {
    int jt = k0 >> 7, koff = k0 & 127;
    const f16* Pt = Pb + (size_t)(tq + jt) * 16384;
    __syncthreads();
#pragma unroll
    for (int c4 = 0; c4 < 4; ++c4) {
      int chunk = c4 * 4 + wave;
      int r = chunk * 8 + srow;
      int cb = sslot ^ (r & 7);
      gload_lds16(Pt + (size_t)r * 128 + koff + cb * 8, As + chunk * 512);
      gload_lds16(vb + (size_t)r * 4096 + k0 + cb * 8, Bs + chunk * 512);
    }
    __syncthreads();

#pragma unroll
    for (int kb = 0; kb < 4; ++kb) {
      int sidx = 2 * kb + h;
      f16x8 af[2], bf[2];
#pragma unroll
      for (int mb = 0; mb < 2; ++mb) {
        int r = wm + mb * 32 + rl;
        af[mb] = *(const f16x8*)(As + r * 64 + (sidx ^ (r & 7)) * 8);
      }
#pragma unroll
      for (int nb = 0; nb < 2; ++nb) {
        int r = wn + nb * 32 + rl;
        bf[nb] = *(const f16x8*)(Bs + r * 64 + (sidx ^ (r & 7)) * 8);
      }
#pragma unroll
      for (int mb = 0; mb < 2; ++mb)
#pragma unroll
        for (int nb = 0; nb < 2; ++nb)
          acc[mb][nb] = MFMA(af[mb], bf[nb], acc[mb][nb]);
    }
  }

  f16* op = (s == 0) ? o0 : (s == 1) ? o1 : (s == 2) ? o2 : o3;
#pragma unroll
  for (int mb = 0; mb < 2; ++mb)
#pragma unroll
    for (int nb = 0; nb < 2; ++nb)
#pragma unroll
      for (int r = 0; r < 16; ++r) {
        int gr = b * 4096 + qt * 128 + wm + mb * 32 + (r & 3) + 8 * (r >> 2) + 4 * h;
        op[(size_t)gr * 128 + wn + nb * 32 + rl] = (f16)acc[mb][nb][r];
      }
}

// ---------------- output projection with fused partial-combine A staging ----------------
// C(16384x1024 fp32) = (sum_s o_s)(16384x128) * Woth(1024x128)^T
__global__ __launch_bounds__(256, 2) void k_gout(const f16* __restrict__ o0,
                                                 const f16* __restrict__ o1,
                                                 const f16* __restrict__ o2,
                                                 const f16* __restrict__ o3,
                                                 const f16* __restrict__ Bt,
                                                 float* __restrict__ C) {
  __shared__ __align__(16) f16 As[128 * 64];
  __shared__ __align__(16) f16 Bs[128 * 64];
  int tid = threadIdx.x;
  int wave = tid >> 6, lane = tid & 63;
  int m0 = blockIdx.y * 128, n0 = blockIdx.x * 128;
  int wm = (wave >> 1) * 64, wn = (wave & 1) * 64;
  int rl = lane & 31, h = lane >> 5;
  int srow = lane >> 3, sslot = lane & 7;
  int qt = (m0 >> 7) & 31;
  int ns = (qt >> 3) + 1;  // number of PV split partials covering this row block
  const f16* srcs[4] = {o0, o1, o2, o3};

  f32x16 acc[2][2];
#pragma unroll
  for (int mb = 0; mb < 2; ++mb)
#pragma unroll
    for (int nb = 0; nb < 2; ++nb)
#pragma unroll
      for (int r = 0; r < 16; ++r) acc[mb][nb][r] = 0.f;

  for (int k0 = 0; k0 < 128; k0 += 64) {
    __syncthreads();
#pragma unroll
    for (int c = 0; c < 4; ++c) {
      int chunk = c * 4 + wave;
      int r = chunk * 8 + srow;
      // A: reg-stage sum of partials, swizzled ds_write
      float sum[8];
#pragma unroll
      for (int e = 0; e < 8; ++e) sum[e] = 0.f;
#pragma unroll
      for (int p = 0; p < 4; ++p) {
        if (p < ns) {
          f16x8 v = *(const f16x8*)(srcs[p] + (size_t)(m0 + r) * 128 + k0 + sslot * 8);
#pragma unroll
          for (int e = 0; e < 8; ++e) sum[e] += (float)v[e];
        }
      }
      f16x8 w;
#pragma unroll
      for (int e = 0; e < 8; ++e) w[e] = (f16)sum[e];
      *(f16x8*)(As + r * 64 + (sslot ^ (r & 7)) * 8) = w;
      // B: async stage
      int cb = sslot ^ (r & 7);
      gload_lds16(Bt + (size_t)(n0 + r) * 128 + k0 + cb * 8, Bs + chunk * 512);
    }
    __syncthreads();

#pragma unroll
    for (int kb = 0; kb < 4; ++kb) {
      int s = 2 * kb + h;
      f16x8 af[2], bf[2];
#pragma unroll
      for (int mb = 0; mb < 2; ++mb) {
        int r = wm + mb * 32 + rl;
        af[mb] = *(const f16x8*)(As + r * 64 + (s ^ (r & 7)) * 8);
      }
#pragma unroll
      for (int nb = 0; nb < 2; ++nb) {
        int r = wn + nb * 32 + rl;
        bf[nb] = *(const f16x8*)(Bs + r * 64 + (s ^ (r & 7)) * 8);
      }
#pragma unroll
      for (int mb = 0; mb < 2; ++mb)
#pragma unroll
        for (int nb = 0; nb < 2; ++nb)
          acc[mb][nb] = MFMA(af[mb], bf[nb], acc[mb][nb]);
    }
  }

#pragma unroll
  for (int mb = 0; mb < 2; ++mb)
#pragma unroll
    for (int nb = 0; nb < 2; ++nb)
#pragma unroll
      for (int r = 0; r < 16; ++r) {
        int i = m0 + wm + mb * 32 + (r & 3) + 8 * (r >> 2) + 4 * h;
        int j = n0 + wn + nb * 32 + rl;
        C[(size_t)i * 1024 + j] = acc[mb][nb][r];
      }
}

// ---------------- launch ----------------
extern "C" void kernel_launch(void* const* d_in, const int* in_sizes, int n_in,
                              void* d_out, int out_size, void* d_ws, size_t ws_size,
                              hipStream_t stream) {
  (void)in_sizes; (void)n_in; (void)out_size; (void)ws_size;
  const float* x  = (const float*)d_in[0];
  const float* cp = (const float*)d_in[1];
  const float* sp = (const float*)d_in[2];
  // d_in[3] = causal_mask (unused; mask computed analytically)
  const float* W[5] = {(const float*)d_in[4], (const float*)d_in[5], (const float*)d_in[6],
                       (const float*)d_in[7], (const float*)d_in[8]};
  const float* Wo = (const float*)d_in[9];
  float* out = (float*)d_out;
  char* ws = (char*)d_ws;

  // workspace layout (bytes):
  // [0, 16M): o0..o3 f16 PV partials (4 MB each); [16M, 48M): xh f16 (32 MB)
  // [48M, 74M): q1h,q2h,k1h,k2h,vh,vt (4 MB each); then Wth, Woth, P (69 MB)
  const size_t OFF_XH   = 16777216;
  const size_t OFF_H    = OFF_XH + 33554432;          // 50331648
  const size_t OFF_WTH  = OFF_H + 6 * 4194304;        // 75497472
  const size_t OFF_WOTH = OFF_WTH + 1310720;
  const size_t OFF_P    = OFF_WOTH + 262144;          // ~77 MB .. 146 MB
  f16*   o0   = (f16*)(ws + 0);
  f16*   o1   = (f16*)(ws + 4194304);
  f16*   o2   = (f16*)(ws + 8388608);
  f16*   o3   = (f16*)(ws + 12582912);
  f16*   xh   = (f16*)(ws + OFF_XH);
  f16*   q1h  = (f16*)(ws + OFF_H + 0 * 4194304);
  f16*   q2h  = (f16*)(ws + OFF_H + 1 * 4194304);
  f16*   k1h  = (f16*)(ws + OFF_H + 2 * 4194304);
  f16*   k2h  = (f16*)(ws + OFF_H + 3 * 4194304);
  f16*   vh   = (f16*)(ws + OFF_H + 4 * 4194304);
  f16*   vt   = (f16*)(ws + OFF_H + 5 * 4194304);
  f16*   Wth  = (f16*)(ws + OFF_WTH);
  f16*   Woth = (f16*)(ws + OFF_WOTH);
  f16*   P    = (f16*)(ws + OFF_P);

  // 1) x -> fp16
  k_cvt_f16<<<16384, 256, 0, stream>>>(x, xh, 4194304);
  // 2) weight transposes (fp32 KxN -> fp16 NxK)
  for (int w = 0; w < 5; ++w)
    k_transpose_cvt<<<dim3(32, 4), 256, 0, stream>>>(W[w], Wth + (size_t)w * 128 * 1024, 1024, 128);
  k_transpose_cvt<<<dim3(4, 32), 256, 0, stream>>>(Wo, Woth, 128, 1024);
  // 3) projections (f16 A, XCD-grouped) with fused RoPE epilogue
  k_proj<<<640, 256, 0, stream>>>(xh, Wth, cp, sp, q1h, q2h, k1h, k2h, vh);
  // 4) V transpose
  k_vtrans16<<<dim3(512, 4), 256, 0, stream>>>(vh, vt);
  // 5) S-phase (packed triangular P)
  k_s<<<2112, 256, 0, stream>>>(q1h, q2h, k1h, k2h, P);
  // 6) PV-phase (split-K f16 partials)
  k_pv<<<320, 256, 0, stream>>>(P, vt, o0, o1, o2, o3);
  // 7) output projection with fused partial combine
  k_gout<<<dim3(8, 128), 256, 0, stream>>>(o0, o1, o2, o3, Woth, out);
}

// Round 6
// 143.448 us; speedup vs baseline: 1.1400x; 1.0552x over previous
//
#include <hip/hip_runtime.h>
#include <stdint.h>
#include <stddef.h>

typedef _Float16 f16;
typedef __attribute__((ext_vector_type(8))) _Float16 f16x8;
typedef __attribute__((ext_vector_type(4))) _Float16 f16x4;
typedef __attribute__((ext_vector_type(16))) float f32x16;
typedef __attribute__((ext_vector_type(4))) float floatx4;

#define MFMA(a, b, c) __builtin_amdgcn_mfma_f32_32x32x16_f16((a), (b), (c), 0, 0, 0)

typedef const __attribute__((address_space(1))) void gvoid_t;
typedef __attribute__((address_space(3))) void svoid_t;

__device__ __forceinline__ void gload_lds16(const void* g, void* l) {
  // wave-uniform LDS base; HW writes lane's 16B at base + lane*16
  __builtin_amdgcn_global_load_lds((gvoid_t*)g, (svoid_t*)l, 16, 0, 0);
}

// ---------------- all weight transposes in one kernel ----------------
// blocks 0..639: Wq1,Wq2,Wk1,Wk2,Wv (1024x128 -> 128x1024 f16)
// blocks 640..767: Wo (128x1024 -> 1024x128 f16)
__global__ __launch_bounds__(256) void k_wtrans(const float* __restrict__ W0,
                                                const float* __restrict__ W1,
                                                const float* __restrict__ W2,
                                                const float* __restrict__ W3,
                                                const float* __restrict__ W4,
                                                const float* __restrict__ Wo,
                                                f16* __restrict__ Wth,
                                                f16* __restrict__ Woth) {
  __shared__ float t[32][33];
  int bid = blockIdx.x;
  const float* W;
  f16* Wt;
  int K, N, k0, n0;
  if (bid < 640) {
    int w = bid >> 7, tt = bid & 127;
    W = (w == 0) ? W0 : (w == 1) ? W1 : (w == 2) ? W2 : (w == 3) ? W3 : W4;
    Wt = Wth + (size_t)w * 128 * 1024;
    K = 1024; N = 128;
    k0 = (tt & 31) * 32; n0 = (tt >> 5) * 32;
  } else {
    int tt = bid - 640;
    W = Wo; Wt = Woth;
    K = 128; N = 1024;
    k0 = (tt & 3) * 32; n0 = (tt >> 2) * 32;
  }
  int tx = threadIdx.x & 31, ty = threadIdx.x >> 5;  // 32 x 8
#pragma unroll
  for (int i = 0; i < 4; ++i)
    t[ty + 8 * i][tx] = W[(size_t)(k0 + ty + 8 * i) * N + n0 + tx];
  __syncthreads();
#pragma unroll
  for (int i = 0; i < 4; ++i)
    Wt[(size_t)(n0 + ty + 8 * i) * K + k0 + tx] = (f16)t[tx][ty + 8 * i];
}

// ---------------- projection GEMM (fp32 x, fused cvt staging), XCD-group, fused RoPE ----------------
// A = x (16384x1024 fp32) reg-staged+converted into the SAME f16 As layout as gload_lds
// would produce (conflict-free b128 writes and reads). Bt = Wth (5 matrices of 128x1024 f16).
// 1-D grid of 640; bid mapping puts the 5 matrix-blocks of one 128-row x-panel
// on the SAME XCD in adjacent issue slots -> panel served from that XCD's L2.
__global__ __launch_bounds__(256, 2) void k_proj(const float* __restrict__ X,
                                                 const f16* __restrict__ Bt,
                                                 const float* __restrict__ cosp,
                                                 const float* __restrict__ sinp,
                                                 f16* __restrict__ q1h, f16* __restrict__ q2h,
                                                 f16* __restrict__ k1h, f16* __restrict__ k2h,
                                                 f16* __restrict__ vh) {
  __shared__ __align__(16) f16 As[128 * 64];
  __shared__ __align__(16) f16 Bs[128 * 64];
  int bid = blockIdx.x;
  int c8 = bid & 7, t = bid >> 3;          // t in 0..79
  int n0 = t % 5;                          // matrix id
  int m0 = (c8 + 8 * (t / 5)) * 128;       // row panel: 5 consecutive turns of XCD c8
  int tid = threadIdx.x;
  int wave = tid >> 6, lane = tid & 63;
  int wm = wave * 32;
  int rl = lane & 31, h = lane >> 5;
  int srow = lane >> 3, sslot = lane & 7;
  const f16* Bmat = Bt + (size_t)n0 * 128 * 1024;

  f32x16 acc[4];
#pragma unroll
  for (int nb = 0; nb < 4; ++nb)
#pragma unroll
    for (int r = 0; r < 16; ++r) acc[nb][r] = 0.f;

  for (int k0 = 0; k0 < 1024; k0 += 64) {
    __syncthreads();
    // B: async direct-to-LDS (issue first so it overlaps the A load+cvt)
#pragma unroll
    for (int c = 0; c < 4; ++c) {
      int chunk = c * 4 + wave;
      int r = chunk * 8 + srow;
      int cb = sslot ^ (r & 7);
      gload_lds16(Bmat + (size_t)r * 1024 + k0 + cb * 8, Bs + chunk * 512);
    }
    // A: reg-staged fp32 load + cvt + conflict-free b128 write (gload-equivalent layout)
#pragma unroll
    for (int c = 0; c < 4; ++c) {
      int chunk = c * 4 + wave;
      int r = chunk * 8 + srow;
      int cb = sslot ^ (r & 7);
      const float* src = X + (size_t)(m0 + r) * 1024 + k0 + cb * 8;
      floatx4 v0 = *(const floatx4*)src;
      floatx4 v1 = *(const floatx4*)(src + 4);
      f16x8 w;
#pragma unroll
      for (int e = 0; e < 4; ++e) { w[e] = (f16)v0[e]; w[e + 4] = (f16)v1[e]; }
      *(f16x8*)(As + chunk * 512 + srow * 64 + sslot * 8) = w;
    }
    __syncthreads();

#pragma unroll
    for (int kb = 0; kb < 4; ++kb) {
      int s = 2 * kb + h;
      int ra = wm + rl;
      f16x8 af = *(const f16x8*)(As + ra * 64 + (s ^ (ra & 7)) * 8);
      f16x8 bf[4];
#pragma unroll
      for (int nb = 0; nb < 4; ++nb) {
        int rb = nb * 32 + rl;
        bf[nb] = *(const f16x8*)(Bs + rb * 64 + (s ^ (rb & 7)) * 8);
      }
#pragma unroll
      for (int nb = 0; nb < 4; ++nb) acc[nb] = MFMA(af, bf[nb], acc[nb]);
    }
  }

  if (n0 == 4) {  // V: plain cvt store
#pragma unroll
    for (int r = 0; r < 16; ++r) {
      int irow = (r & 3) + 8 * (r >> 2) + 4 * h;
      int gr = m0 + wm + irow;
#pragma unroll
      for (int nb = 0; nb < 4; ++nb)
        vh[(size_t)gr * 128 + nb * 32 + rl] = (f16)acc[nb][r];
    }
  } else {
    f16* outp = (n0 == 0) ? q1h : (n0 == 1) ? q2h : (n0 == 2) ? k1h : k2h;
#pragma unroll
    for (int r = 0; r < 16; ++r) {
      int irow = (r & 3) + 8 * (r >> 2) + 4 * h;
      int gr = m0 + wm + irow;
      int s = gr & 4095;
#pragma unroll
      for (int nb = 0; nb < 2; ++nb) {
        int d = nb * 32 + rl;
        float c = cosp[s * 64 + d], sn = sinp[s * 64 + d];
        float a = acc[nb][r], bb = acc[nb + 2][r];
        outp[(size_t)gr * 128 + d]      = (f16)(a * c - bb * sn);
        outp[(size_t)gr * 128 + 64 + d] = (f16)(a * sn + bb * c);
      }
    }
  }
}

// ---------------- V transpose (f16): vh(16384x128) -> vt[b][d][s] ----------------
__global__ __launch_bounds__(256) void k_vtrans16(const f16* __restrict__ vh,
                                                  f16* __restrict__ vt) {
  __shared__ unsigned short t[32][33];
  int r0 = blockIdx.x * 32, d0 = blockIdx.y * 32;
  int tx = threadIdx.x & 31, ty = threadIdx.x >> 5;
#pragma unroll
  for (int i = 0; i < 4; ++i)
    t[ty + 8 * i][tx] = ((const unsigned short*)vh)[(size_t)(r0 + ty + 8 * i) * 128 + d0 + tx];
  __syncthreads();
  int b = r0 >> 12, s0 = r0 & 4095;
#pragma unroll
  for (int i = 0; i < 4; ++i)
    ((unsigned short*)vt)[((size_t)(b * 128 + d0 + ty + 8 * i)) * 4096 + s0 + tx] =
        t[tx][ty + 8 * i];
}

// ---------------- S-phase: P = mask(S1*S2)/128, packed lower-triangle tiles ----------------
__global__ __launch_bounds__(256, 2) void k_s(const f16* __restrict__ q1h,
                                              const f16* __restrict__ q2h,
                                              const f16* __restrict__ k1h,
                                              const f16* __restrict__ k2h,
                                              f16* __restrict__ P) {
  __shared__ __align__(16) f16 A1[128 * 64];
  __shared__ __align__(16) f16 A2[128 * 64];
  __shared__ __align__(16) f16 B1[128 * 64];
  __shared__ __align__(16) f16 B2[128 * 64];
  int bid0 = blockIdx.x;
  int bid = (bid0 & 7) * 264 + (bid0 >> 3);  // XCD-contiguous chunks (2112 = 8*264)
  int b = bid / 528, t = bid % 528;
  int i = (int)((sqrtf(8.f * t + 1.f) - 1.f) * 0.5f);
  if ((i + 1) * (i + 2) / 2 <= t) ++i;
  if (i * (i + 1) / 2 > t) --i;
  int j = t - i * (i + 1) / 2;

  int tid = threadIdx.x;
  int wave = tid >> 6, lane = tid & 63;
  int wm = (wave >> 1) * 64, wn = (wave & 1) * 64;
  int rl = lane & 31, h = lane >> 5;
  int srow = lane >> 3, sslot = lane & 7;
  size_t rowA = (size_t)b * 4096 + i * 128;
  size_t rowB = (size_t)b * 4096 + j * 128;

  f32x16 acc1[2][2], acc2[2][2];
#pragma unroll
  for (int mb = 0; mb < 2; ++mb)
#pragma unroll
    for (int nb = 0; nb < 2; ++nb)
#pragma unroll
      for (int r = 0; r < 16; ++r) { acc1[mb][nb][r] = 0.f; acc2[mb][nb][r] = 0.f; }

  for (int k0 = 0; k0 < 128; k0 += 64) {
    __syncthreads();
#pragma unroll
    for (int c = 0; c < 4; ++c) {
      int chunk = c * 4 + wave;
      int r = chunk * 8 + srow;
      int cb = sslot ^ (r & 7);
      gload_lds16(q1h + (rowA + r) * 128 + k0 + cb * 8, A1 + chunk * 512);
      gload_lds16(q2h + (rowA + r) * 128 + k0 + cb * 8, A2 + chunk * 512);
      gload_lds16(k1h + (rowB + r) * 128 + k0 + cb * 8, B1 + chunk * 512);
      gload_lds16(k2h + (rowB + r) * 128 + k0 + cb * 8, B2 + chunk * 512);
    }
    __syncthreads();

#pragma unroll
    for (int kb = 0; kb < 4; ++kb) {
      int s = 2 * kb + h;
      f16x8 a1f[2], a2f[2], b1f[2], b2f[2];
#pragma unroll
      for (int mb = 0; mb < 2; ++mb) {
        int r = wm + mb * 32 + rl;
        int off = r * 64 + (s ^ (r & 7)) * 8;
        a1f[mb] = *(const f16x8*)(A1 + off);
        a2f[mb] = *(const f16x8*)(A2 + off);
      }
#pragma unroll
      for (int nb = 0; nb < 2; ++nb) {
        int r = wn + nb * 32 + rl;
        int off = r * 64 + (s ^ (r & 7)) * 8;
        b1f[nb] = *(const f16x8*)(B1 + off);
        b2f[nb] = *(const f16x8*)(B2 + off);
      }
#pragma unroll
      for (int mb = 0; mb < 2; ++mb)
#pragma unroll
        for (int nb = 0; nb < 2; ++nb) {
          acc1[mb][nb] = MFMA(a1f[mb], b1f[nb], acc1[mb][nb]);
          acc2[mb][nb] = MFMA(a2f[mb], b2f[nb], acc2[mb][nb]);
        }
    }
  }

  f16* pt = P + ((size_t)b * 528 + t) * 16384;
  bool diag = (i == j);
#pragma unroll
  for (int mb = 0; mb < 2; ++mb)
#pragma unroll
    for (int nb = 0; nb < 2; ++nb)
#pragma unroll
      for (int r = 0; r < 16; ++r) {
        int row_l = wm + mb * 32 + (r & 3) + 8 * (r >> 2) + 4 * h;
        int col_l = wn + nb * 32 + rl;
        float p = acc1[mb][nb][r] * acc2[mb][nb][r] * (1.0f / 128.0f);
        if (diag && col_l > row_l) p = 0.f;
        pt[(size_t)row_l * 128 + col_l] = (f16)p;
      }
}

// ---------------- PV-phase: O_partial = P_packed * V^T, split-K over 1024-key chunks ----------------
__global__ __launch_bounds__(256, 2) void k_pv(const f16* __restrict__ P,
                                               const f16* __restrict__ vt,
                                               f16* __restrict__ o0, f16* __restrict__ o1,
                                               f16* __restrict__ o2, f16* __restrict__ o3) {
  __shared__ __align__(16) f16 As[128 * 64];
  __shared__ __align__(16) f16 Bs[128 * 64];
  int bid = blockIdx.x;
  int b = bid / 80, c = bid % 80;
  int qt, s;
  if (c < 8)       { qt = c;                 s = 0; }
  else if (c < 24) { int t = c - 8;  qt = 8  + (t >> 1); s = t & 1; }
  else if (c < 48) { int t = c - 24; qt = 16 + t / 3;    s = t - 3 * (t / 3); }
  else             { int t = c - 48; qt = 24 + (t >> 2); s = t & 3; }
  int tq = qt * (qt + 1) / 2;
  const f16* Pb = P + (size_t)b * 528 * 16384;
  const f16* vb = vt + (size_t)b * 128 * 4096;
  int kbase = s * 1024;
  int kend = (qt + 1) * 128 < kbase + 1024 ? (qt + 1) * 128 : kbase + 1024;

  int tid = threadIdx.x;
  int wave = tid >> 6, lane = tid & 63;
  int wm = (wave >> 1) * 64, wn = (wave & 1) * 64;
  int rl = lane & 31, h = lane >> 5;
  int srow = lane >> 3, sslot = lane & 7;

  f32x16 acc[2][2];
#pragma unroll
  for (int mb = 0; mb < 2; ++mb)
#pragma unroll
    for (int nb = 0; nb < 2; ++nb)
#pragma unroll
      for (int r = 0; r < 16; ++r) acc[mb][nb][r] = 0.f;

  for (int k0 = kbase; k0 < kend; k0 += 64) {
    int jt = k0 >> 7, koff = k0 & 127;
    const f16* Pt = Pb + (size_t)(tq + jt) * 16384;
    __syncthreads();
#pragma unroll
    for (int c4 = 0; c4 < 4; ++c4) {
      int chunk = c4 * 4 + wave;
      int r = chunk * 8 + srow;
      int cb = sslot ^ (r & 7);
      gload_lds16(Pt + (size_t)r * 128 + koff + cb * 8, As + chunk * 512);
      gload_lds16(vb + (size_t)r * 4096 + k0 + cb * 8, Bs + chunk * 512);
    }
    __syncthreads();

#pragma unroll
    for (int kb = 0; kb < 4; ++kb) {
      int sidx = 2 * kb + h;
      f16x8 af[2], bf[2];
#pragma unroll
      for (int mb = 0; mb < 2; ++mb) {
        int r = wm + mb * 32 + rl;
        af[mb] = *(const f16x8*)(As + r * 64 + (sidx ^ (r & 7)) * 8);
      }
#pragma unroll
      for (int nb = 0; nb < 2; ++nb) {
        int r = wn + nb * 32 + rl;
        bf[nb] = *(const f16x8*)(Bs + r * 64 + (sidx ^ (r & 7)) * 8);
      }
#pragma unroll
      for (int mb = 0; mb < 2; ++mb)
#pragma unroll
        for (int nb = 0; nb < 2; ++nb)
          acc[mb][nb] = MFMA(af[mb], bf[nb], acc[mb][nb]);
    }
  }

  f16* op = (s == 0) ? o0 : (s == 1) ? o1 : (s == 2) ? o2 : o3;
#pragma unroll
  for (int mb = 0; mb < 2; ++mb)
#pragma unroll
    for (int nb = 0; nb < 2; ++nb)
#pragma unroll
      for (int r = 0; r < 16; ++r) {
        int gr = b * 4096 + qt * 128 + wm + mb * 32 + (r & 3) + 8 * (r >> 2) + 4 * h;
        op[(size_t)gr * 128 + wn + nb * 32 + rl] = (f16)acc[mb][nb][r];
      }
}

// ---------------- output projection with fused partial-combine A staging ----------------
// C(16384x1024 fp32) = (sum_s o_s)(16384x128) * Woth(1024x128)^T
__global__ __launch_bounds__(256, 2) void k_gout(const f16* __restrict__ o0,
                                                 const f16* __restrict__ o1,
                                                 const f16* __restrict__ o2,
                                                 const f16* __restrict__ o3,
                                                 const f16* __restrict__ Bt,
                                                 float* __restrict__ C) {
  __shared__ __align__(16) f16 As[128 * 64];
  __shared__ __align__(16) f16 Bs[128 * 64];
  int tid = threadIdx.x;
  int wave = tid >> 6, lane = tid & 63;
  int m0 = blockIdx.y * 128, n0 = blockIdx.x * 128;
  int wm = (wave >> 1) * 64, wn = (wave & 1) * 64;
  int rl = lane & 31, h = lane >> 5;
  int srow = lane >> 3, sslot = lane & 7;
  int qt = (m0 >> 7) & 31;
  int ns = (qt >> 3) + 1;  // number of PV split partials covering this row block
  const f16* srcs[4] = {o0, o1, o2, o3};

  f32x16 acc[2][2];
#pragma unroll
  for (int mb = 0; mb < 2; ++mb)
#pragma unroll
    for (int nb = 0; nb < 2; ++nb)
#pragma unroll
      for (int r = 0; r < 16; ++r) acc[mb][nb][r] = 0.f;

  for (int k0 = 0; k0 < 128; k0 += 64) {
    __syncthreads();
#pragma unroll
    for (int c = 0; c < 4; ++c) {
      int chunk = c * 4 + wave;
      int r = chunk * 8 + srow;
      // A: reg-stage sum of partials, swizzled ds_write
      float sum[8];
#pragma unroll
      for (int e = 0; e < 8; ++e) sum[e] = 0.f;
#pragma unroll
      for (int p = 0; p < 4; ++p) {
        if (p < ns) {
          f16x8 v = *(const f16x8*)(srcs[p] + (size_t)(m0 + r) * 128 + k0 + sslot * 8);
#pragma unroll
          for (int e = 0; e < 8; ++e) sum[e] += (float)v[e];
        }
      }
      f16x8 w;
#pragma unroll
      for (int e = 0; e < 8; ++e) w[e] = (f16)sum[e];
      *(f16x8*)(As + r * 64 + (sslot ^ (r & 7)) * 8) = w;
      // B: async stage
      int cb = sslot ^ (r & 7);
      gload_lds16(Bt + (size_t)(n0 + r) * 128 + k0 + cb * 8, Bs + chunk * 512);
    }
    __syncthreads();

#pragma unroll
    for (int kb = 0; kb < 4; ++kb) {
      int s = 2 * kb + h;
      f16x8 af[2], bf[2];
#pragma unroll
      for (int mb = 0; mb < 2; ++mb) {
        int r = wm + mb * 32 + rl;
        af[mb] = *(const f16x8*)(As + r * 64 + (s ^ (r & 7)) * 8);
      }
#pragma unroll
      for (int nb = 0; nb < 2; ++nb) {
        int r = wn + nb * 32 + rl;
        bf[nb] = *(const f16x8*)(Bs + r * 64 + (s ^ (r & 7)) * 8);
      }
#pragma unroll
      for (int mb = 0; mb < 2; ++mb)
#pragma unroll
        for (int nb = 0; nb < 2; ++nb)
          acc[mb][nb] = MFMA(af[mb], bf[nb], acc[mb][nb]);
    }
  }

#pragma unroll
  for (int mb = 0; mb < 2; ++mb)
#pragma unroll
    for (int nb = 0; nb < 2; ++nb)
#pragma unroll
      for (int r = 0; r < 16; ++r) {
        int i = m0 + wm + mb * 32 + (r & 3) + 8 * (r >> 2) + 4 * h;
        int j = n0 + wn + nb * 32 + rl;
        C[(size_t)i * 1024 + j] = acc[mb][nb][r];
      }
}

// ---------------- launch ----------------
extern "C" void kernel_launch(void* const* d_in, const int* in_sizes, int n_in,
                              void* d_out, int out_size, void* d_ws, size_t ws_size,
                              hipStream_t stream) {
  (void)in_sizes; (void)n_in; (void)out_size; (void)ws_size;
  const float* x  = (const float*)d_in[0];
  const float* cp = (const float*)d_in[1];
  const float* sp = (const float*)d_in[2];
  // d_in[3] = causal_mask (unused; mask computed analytically)
  const float* W[5] = {(const float*)d_in[4], (const float*)d_in[5], (const float*)d_in[6],
                       (const float*)d_in[7], (const float*)d_in[8]};
  const float* Wo = (const float*)d_in[9];
  float* out = (float*)d_out;
  char* ws = (char*)d_ws;

  // workspace layout (bytes):
  // [0, 16M): o0..o3 f16 PV partials (4 MB each)
  // [16M, 40M): q1h,q2h,k1h,k2h,vh,vt (4 MB each); then Wth (1.25M), Woth (0.25M), P (69M)
  const size_t OFF_H    = 16777216;
  const size_t OFF_WTH  = OFF_H + 6 * 4194304;
  const size_t OFF_WOTH = OFF_WTH + 1310720;
  const size_t OFF_P    = OFF_WOTH + 262144;
  f16*   o0   = (f16*)(ws + 0);
  f16*   o1   = (f16*)(ws + 4194304);
  f16*   o2   = (f16*)(ws + 8388608);
  f16*   o3   = (f16*)(ws + 12582912);
  f16*   q1h  = (f16*)(ws + OFF_H + 0 * 4194304);
  f16*   q2h  = (f16*)(ws + OFF_H + 1 * 4194304);
  f16*   k1h  = (f16*)(ws + OFF_H + 2 * 4194304);
  f16*   k2h  = (f16*)(ws + OFF_H + 3 * 4194304);
  f16*   vh   = (f16*)(ws + OFF_H + 4 * 4194304);
  f16*   vt   = (f16*)(ws + OFF_H + 5 * 4194304);
  f16*   Wth  = (f16*)(ws + OFF_WTH);
  f16*   Woth = (f16*)(ws + OFF_WOTH);
  f16*   P    = (f16*)(ws + OFF_P);

  // 1) all weight transposes (one kernel)
  k_wtrans<<<768, 256, 0, stream>>>(W[0], W[1], W[2], W[3], W[4], Wo, Wth, Woth);
  // 2) projections from fp32 x (fused cvt staging, XCD-grouped) with fused RoPE
  k_proj<<<640, 256, 0, stream>>>(x, Wth, cp, sp, q1h, q2h, k1h, k2h, vh);
  // 3) V transpose
  k_vtrans16<<<dim3(512, 4), 256, 0, stream>>>(vh, vt);
  // 4) S-phase (packed triangular P)
  k_s<<<2112, 256, 0, stream>>>(q1h, q2h, k1h, k2h, P);
  // 5) PV-phase (split-K f16 partials)
  k_pv<<<320, 256, 0, stream>>>(P, vt, o0, o1, o2, o3);
  // 6) output projection with fused partial combine
  k_gout<<<dim3(8, 128), 256, 0, stream>>>(o0, o1, o2, o3, Woth, out);
}